// Round 1
// baseline (91828.693 us; speedup 1.0000x reference)
//
#include <hip/hip_runtime.h>
#include <stdint.h>

#define SEQ 8192
#define EMB 1024
#define HID 2048
#define NCH 256

#define SCAN_B 128                  // persistent blocks (all co-resident on 256 CUs)
#define SCAN_T 512                  // 8 waves/block
#define ROWS_PB (HID / SCAN_B)      // 16 rows of h per block
// thread layout in scan: row_local = tid>>5 (0..15), sub = tid&31, cols [sub*64, sub*64+64)

// ---------------------------------------------------------------------------
// Generic fp32 "TN" GEMM: C[m][n] = bias[n] + dot(X[m][:], W[n][:])
// X: [M][K] row-major, W: [N][K] row-major. 64x64 tile, 256 thr, 4x4 microtile.
// Used for P = emb @ wax^T + wax_b and out = H[1:] @ wya^T + wya_b.
// ---------------------------------------------------------------------------
__global__ __launch_bounds__(256) void gemm_tn(const float* __restrict__ X,
                                               const float* __restrict__ W,
                                               const float* __restrict__ bias,
                                               float* __restrict__ C,
                                               int M, int N, int K)
{
    __shared__ float Xs[16][68];   // [k][m], stride 68 keeps float4 reads 16B-aligned
    __shared__ float Ws[16][68];   // [k][n]
    const int m0 = blockIdx.x * 64, n0 = blockIdx.y * 64;
    const int tid  = threadIdx.x;
    const int lrow = tid >> 2;          // 0..63 (tile row for loading)
    const int kq   = (tid & 3) * 4;     // 0,4,8,12 (k quad for loading)
    const int tx   = tid & 15, ty = tid >> 4;
    float acc[4][4] = {};
    const float* Xp = X + (size_t)(m0 + lrow) * K + kq;
    const float* Wp = W + (size_t)(n0 + lrow) * K + kq;

    for (int k0 = 0; k0 < K; k0 += 16) {
        float4 xv = *(const float4*)(Xp + k0);
        float4 wv = *(const float4*)(Wp + k0);
        __syncthreads();
        Xs[kq+0][lrow] = xv.x; Xs[kq+1][lrow] = xv.y;
        Xs[kq+2][lrow] = xv.z; Xs[kq+3][lrow] = xv.w;
        Ws[kq+0][lrow] = wv.x; Ws[kq+1][lrow] = wv.y;
        Ws[kq+2][lrow] = wv.z; Ws[kq+3][lrow] = wv.w;
        __syncthreads();
#pragma unroll
        for (int kk = 0; kk < 16; ++kk) {
            float4 av = *(const float4*)&Xs[kk][ty * 4];
            float4 bv = *(const float4*)&Ws[kk][tx * 4];
            float a[4] = {av.x, av.y, av.z, av.w};
            float b[4] = {bv.x, bv.y, bv.z, bv.w};
#pragma unroll
            for (int i = 0; i < 4; ++i)
#pragma unroll
                for (int j = 0; j < 4; ++j)
                    acc[i][j] += a[i] * b[j];
        }
    }
#pragma unroll
    for (int i = 0; i < 4; ++i) {
        const int m = m0 + ty * 4 + i;
#pragma unroll
        for (int j = 0; j < 4; ++j) {
            const int n = n0 + tx * 4 + j;
            C[(size_t)m * N + n] = acc[i][j] + bias[n];
        }
    }
}

// ---------------------------------------------------------------------------
// Persistent RNN scan. W (waa) lives in VGPRs: block b owns rows
// [b*16, b*16+16); thread = (row_local = tid>>5, sub = tid&31) holds
// waa[row][sub*64 .. sub*64+64) -> 64 fp32 VGPRs.
// Per step: poll flags of previous step (wave 0 only), acquire fence,
// read h_prev (8KB) from H, 64 FMAs, half-wave shuffle reduce, tanh,
// store h_new row chunk, release fence + per-block flag.
// ---------------------------------------------------------------------------
__global__ __launch_bounds__(SCAN_T, 2) void rnn_scan(
    const int*  __restrict__ seq,
    const float* __restrict__ waa,
    const float* __restrict__ P,
    float* __restrict__ H,                 // (SEQ+1) x HID, row 0 zeroed
    unsigned int* __restrict__ flags)      // SEQ x SCAN_B, zeroed
{
    const int b    = blockIdx.x;
    const int tid  = threadIdx.x;
    const int rl   = tid >> 5;        // 0..15
    const int sub  = tid & 31;        // 0..31
    const int grow = b * ROWS_PB + rl;
    const int lane = tid & 63;

    // Load this thread's 64 weights into registers (read once, 16 MB total).
    float w[64];
    {
        const float* wr = waa + (size_t)grow * HID + sub * 64;
#pragma unroll
        for (int k = 0; k < 16; ++k) {
            float4 v = ((const float4*)wr)[k];
            w[4*k+0] = v.x; w[4*k+1] = v.y; w[4*k+2] = v.z; w[4*k+3] = v.w;
        }
    }

    for (int t = 0; t < SEQ; ++t) {
        // Prefetch xa for this step (independent of the flag wait).
        const int ch = seq[t];
        float xav = 0.f;
        if (sub == 0) xav = P[(size_t)ch * HID + grow];

        if (t > 0) {
            if (tid < 64) {   // wave 0 polls: 2 flags per lane covers 128 blocks
                unsigned int* fl = flags + (size_t)(t - 1) * SCAN_B;
                for (;;) {
                    unsigned int f0 = __hip_atomic_load(fl + 2*lane,     __ATOMIC_RELAXED, __HIP_MEMORY_SCOPE_AGENT);
                    unsigned int f1 = __hip_atomic_load(fl + 2*lane + 1, __ATOMIC_RELAXED, __HIP_MEMORY_SCOPE_AGENT);
                    if (__ballot((f0 != 0u) && (f1 != 0u)) == ~0ull) break;
                }
                __threadfence();   // acquire: invalidate L1/L2 before reading H[t]
            }
            __syncthreads();       // gate all waves' reads behind the acquire
        }

        // h_prev dot: 64 contiguous floats per thread from H[t].
        const float* hrow = H + (size_t)t * HID + sub * 64;
        float acc = 0.f;
#pragma unroll
        for (int k = 0; k < 16; ++k) {
            float4 hv = ((const float4*)hrow)[k];
            acc += w[4*k+0]*hv.x + w[4*k+1]*hv.y + w[4*k+2]*hv.z + w[4*k+3]*hv.w;
        }
        // Reduce across the 32 lanes of this row (half-wave butterfly).
#pragma unroll
        for (int off = 16; off > 0; off >>= 1)
            acc += __shfl_xor(acc, off, 32);

        if (sub == 0)
            H[(size_t)(t + 1) * HID + grow] = tanhf(xav + acc);

        __syncthreads();           // all stores drained (vmcnt0 at barrier)
        if (tid == 0) {
            __threadfence();       // release: flush dirty L2 lines to L3
            __hip_atomic_store(flags + (size_t)t * SCAN_B + b, 1u,
                               __ATOMIC_RELAXED, __HIP_MEMORY_SCOPE_AGENT);
        }
    }
}

__global__ void copy_h(const float* __restrict__ src, float* __restrict__ dst)
{
    int i = blockIdx.x * blockDim.x + threadIdx.x;
    if (i < HID) dst[i] = src[i];
}

// ---------------------------------------------------------------------------
extern "C" void kernel_launch(void* const* d_in, const int* in_sizes, int n_in,
                              void* d_out, int out_size, void* d_ws, size_t ws_size,
                              hipStream_t stream)
{
    const int*   seq  = (const int*)  d_in[0];
    const float* emb  = (const float*)d_in[1];
    const float* wax  = (const float*)d_in[2];
    const float* waxb = (const float*)d_in[3];
    const float* waa  = (const float*)d_in[4];
    const float* wya  = (const float*)d_in[5];
    const float* wyab = (const float*)d_in[6];
    float* out = (float*)d_out;

    // ws layout: H[(SEQ+1)][HID] fp32 | flags[SEQ][SCAN_B] u32 | P[NCH][HID] fp32
    float*        H     = (float*)d_ws;
    unsigned int* flags = (unsigned int*)((char*)d_ws + (size_t)(SEQ + 1) * HID * sizeof(float));
    float*        P     = (float*)((char*)flags + (size_t)SEQ * SCAN_B * sizeof(unsigned int));

    // ws is poisoned 0xAA before every timed launch: zero h0 row and flags.
    hipMemsetAsync(H, 0, HID * sizeof(float), stream);
    hipMemsetAsync(flags, 0, (size_t)SEQ * SCAN_B * sizeof(unsigned int), stream);

    // P = emb @ wax^T + wax_b   (M=256, N=2048, K=1024)
    dim3 gA(NCH / 64, HID / 64);
    gemm_tn<<<gA, 256, 0, stream>>>(emb, wax, waxb, P, NCH, HID, EMB);

    // Sequential recurrence (persistent kernel, flag-synced).
    rnn_scan<<<SCAN_B, SCAN_T, 0, stream>>>(seq, waa, P, H, flags);

    // out = H[1..SEQ] @ wya^T + wya_b   (M=8192, N=256, K=2048)
    dim3 gC(SEQ / 64, NCH / 64);
    gemm_tn<<<gC, 256, 0, stream>>>(H + HID, wya, wyab, out, SEQ, NCH, HID);

    // h_final = H[SEQ] -> d_out tail
    copy_h<<<(HID + 255) / 256, 256, 0, stream>>>(H + (size_t)SEQ * HID,
                                                  out + (size_t)SEQ * NCH);
}

// Round 2
// 29463.452 us; speedup vs baseline: 3.1167x; 3.1167x over previous
//
#include <hip/hip_runtime.h>
#include <stdint.h>

#define SEQ 8192
#define EMB 1024
#define HID 2048
#define NCH 256

#define SCAN_B 128                  // persistent blocks, 1 per CU (<=256) -> co-resident
#define SCAN_T 512                  // 8 waves/block
#define ROWS_PB (HID / SCAN_B)      // 16 rows of h per block
#define SENT 0xFFFFFFFFu            // -NaN bit pattern: tanh never produces it

// ---------------------------------------------------------------------------
// Generic fp32 "TN" GEMM: C[m][n] = bias[n] + dot(X[m][:], W[n][:])
// X: [M][K] row-major, W: [N][K] row-major. 64x64 tile, 256 thr, 4x4 microtile.
// ---------------------------------------------------------------------------
__global__ __launch_bounds__(256) void gemm_tn(const float* __restrict__ X,
                                               const float* __restrict__ W,
                                               const float* __restrict__ bias,
                                               float* __restrict__ C,
                                               int M, int N, int K)
{
    __shared__ float Xs[16][68];
    __shared__ float Ws[16][68];
    const int m0 = blockIdx.x * 64, n0 = blockIdx.y * 64;
    const int tid  = threadIdx.x;
    const int lrow = tid >> 2;
    const int kq   = (tid & 3) * 4;
    const int tx   = tid & 15, ty = tid >> 4;
    float acc[4][4] = {};
    const float* Xp = X + (size_t)(m0 + lrow) * K + kq;
    const float* Wp = W + (size_t)(n0 + lrow) * K + kq;

    for (int k0 = 0; k0 < K; k0 += 16) {
        float4 xv = *(const float4*)(Xp + k0);
        float4 wv = *(const float4*)(Wp + k0);
        __syncthreads();
        Xs[kq+0][lrow] = xv.x; Xs[kq+1][lrow] = xv.y;
        Xs[kq+2][lrow] = xv.z; Xs[kq+3][lrow] = xv.w;
        Ws[kq+0][lrow] = wv.x; Ws[kq+1][lrow] = wv.y;
        Ws[kq+2][lrow] = wv.z; Ws[kq+3][lrow] = wv.w;
        __syncthreads();
#pragma unroll
        for (int kk = 0; kk < 16; ++kk) {
            float4 av = *(const float4*)&Xs[kk][ty * 4];
            float4 bv = *(const float4*)&Ws[kk][tx * 4];
            float a[4] = {av.x, av.y, av.z, av.w};
            float b[4] = {bv.x, bv.y, bv.z, bv.w};
#pragma unroll
            for (int i = 0; i < 4; ++i)
#pragma unroll
                for (int j = 0; j < 4; ++j)
                    acc[i][j] += a[i] * b[j];
        }
    }
#pragma unroll
    for (int i = 0; i < 4; ++i) {
        const int m = m0 + ty * 4 + i;
#pragma unroll
        for (int j = 0; j < 4; ++j) {
            const int n = n0 + tx * 4 + j;
            C[(size_t)m * N + n] = acc[i][j] + bias[n];
        }
    }
}

// ---------------------------------------------------------------------------
// Persistent RNN scan, fence-free protocol:
//   H rows 1..SEQ pre-filled with 0xFFFFFFFF (NaN). Producers write h words
//   with relaxed AGENT-scope atomic stores (per-word coherent-point write).
//   Consumers poll their needed words with relaxed AGENT-scope atomic loads
//   until != sentinel. Data is self-validating -> no fences, no flags.
// Thread (rl = tid>>5, sub = tid&31) owns row grow = b*16+rl and columns
//   col(j,e) = 128*j + 4*sub + e  (j=0..15, e=0..3)  -> 64 weights in VGPRs.
// LDS h-buffer is double-buffered; ONE __syncthreads per step keeps each
// block internally within one step of itself, so parity-2 reuse is safe.
// ---------------------------------------------------------------------------
__global__ __launch_bounds__(SCAN_T, 2) void rnn_scan(
    const int*  __restrict__ seq,
    const float* __restrict__ waa,
    const float* __restrict__ P,
    float* __restrict__ H)                 // (SEQ+1) x HID; row0 = 0, rest = SENT
{
    const int b    = blockIdx.x;
    const int tid  = threadIdx.x;
    const int rl   = tid >> 5;        // 0..15
    const int sub  = tid & 31;        // 0..31
    const int grow = b * ROWS_PB + rl;

    __shared__ float hbuf[2][HID];    // 16 KB, parity-buffered

    // One-time weight load: 64 fp32 per thread, pinned into VGPRs.
    float w[64];
    {
        const float* wr = waa + (size_t)grow * HID + 4 * sub;
#pragma unroll
        for (int j = 0; j < 16; ++j) {
            float4 v = *(const float4*)(wr + 128 * j);
            w[4*j+0] = v.x; w[4*j+1] = v.y; w[4*j+2] = v.z; w[4*j+3] = v.w;
        }
    }
#pragma unroll
    for (int k = 0; k < 64; ++k) asm volatile("" : "+v"(w[k]));  // defeat remat

    unsigned* Hw = (unsigned*)H;

    for (int t = 0; t < SEQ; ++t) {
        // xa prefetch (read-only, cached) — independent of the poll.
        const int ch = seq[t];
        float xav = 0.f;
        if (sub == 0) xav = P[(size_t)ch * HID + grow];

        // Poll my 4 words of H[t] straight from the coherence point.
        {
            const unsigned* p = Hw + (size_t)t * HID + tid * 4;
            unsigned v0, v1, v2, v3;
            for (;;) {
                v0 = __hip_atomic_load(p + 0, __ATOMIC_RELAXED, __HIP_MEMORY_SCOPE_AGENT);
                v1 = __hip_atomic_load(p + 1, __ATOMIC_RELAXED, __HIP_MEMORY_SCOPE_AGENT);
                v2 = __hip_atomic_load(p + 2, __ATOMIC_RELAXED, __HIP_MEMORY_SCOPE_AGENT);
                v3 = __hip_atomic_load(p + 3, __ATOMIC_RELAXED, __HIP_MEMORY_SCOPE_AGENT);
                if (v0 != SENT && v1 != SENT && v2 != SENT && v3 != SENT) break;
            }
            float4 f;
            f.x = __uint_as_float(v0); f.y = __uint_as_float(v1);
            f.z = __uint_as_float(v2); f.w = __uint_as_float(v3);
            *(float4*)&hbuf[t & 1][tid * 4] = f;
        }
        __syncthreads();

        // 64 FMAs from LDS (4-way-conflict float4 reads ~= free).
        float acc = 0.f;
        const float* hb = &hbuf[t & 1][4 * sub];
#pragma unroll
        for (int j = 0; j < 16; ++j) {
            float4 hv = *(const float4*)(hb + 128 * j);
            acc += w[4*j+0]*hv.x + w[4*j+1]*hv.y + w[4*j+2]*hv.z + w[4*j+3]*hv.w;
        }
        // Reduce across the 32 lanes of this row (half-wave butterfly).
#pragma unroll
        for (int off = 16; off > 0; off >>= 1)
            acc += __shfl_xor(acc, off, 32);

        if (sub == 0) {
            float hn = tanhf(xav + acc);
            __hip_atomic_store(Hw + (size_t)(t + 1) * HID + grow,
                               __float_as_uint(hn),
                               __ATOMIC_RELAXED, __HIP_MEMORY_SCOPE_AGENT);
        }
        // no trailing barrier: parity buffer + per-step barrier make reuse safe
    }
}

__global__ void copy_h(const float* __restrict__ src, float* __restrict__ dst)
{
    int i = blockIdx.x * blockDim.x + threadIdx.x;
    if (i < HID) dst[i] = src[i];
}

// ---------------------------------------------------------------------------
extern "C" void kernel_launch(void* const* d_in, const int* in_sizes, int n_in,
                              void* d_out, int out_size, void* d_ws, size_t ws_size,
                              hipStream_t stream)
{
    const int*   seq  = (const int*)  d_in[0];
    const float* emb  = (const float*)d_in[1];
    const float* wax  = (const float*)d_in[2];
    const float* waxb = (const float*)d_in[3];
    const float* waa  = (const float*)d_in[4];
    const float* wya  = (const float*)d_in[5];
    const float* wyab = (const float*)d_in[6];
    float* out = (float*)d_out;

    // ws layout: H[(SEQ+1)][HID] fp32 | P[NCH][HID] fp32
    float* H = (float*)d_ws;
    float* P = (float*)((char*)d_ws + (size_t)(SEQ + 1) * HID * sizeof(float));

    // Re-init every call (ws re-poisoned to 0xAA before each timed launch):
    // row 0 of H = zeros (h0); rows 1..SEQ = 0xFFFFFFFF sentinel (NaN).
    hipMemsetAsync(H, 0, HID * sizeof(float), stream);
    hipMemsetAsync(H + HID, 0xFF, (size_t)SEQ * HID * sizeof(float), stream);

    // P = emb @ wax^T + wax_b   (M=256, N=2048, K=1024)
    dim3 gA(NCH / 64, HID / 64);
    gemm_tn<<<gA, 256, 0, stream>>>(emb, wax, waxb, P, NCH, HID, EMB);

    // Sequential recurrence (persistent, fence-free sentinel sync).
    rnn_scan<<<SCAN_B, SCAN_T, 0, stream>>>(seq, waa, P, H);

    // out = H[1..SEQ] @ wya^T + wya_b   (M=8192, N=256, K=2048)
    dim3 gC(SEQ / 64, NCH / 64);
    gemm_tn<<<gC, 256, 0, stream>>>(H + HID, wya, wyab, out, SEQ, NCH, HID);

    // h_final = H[SEQ] -> tail of d_out
    copy_h<<<(HID + 255) / 256, 256, 0, stream>>>(H + (size_t)SEQ * HID,
                                                  out + (size_t)SEQ * NCH);
}

// Round 3
// 23574.405 us; speedup vs baseline: 3.8953x; 1.2498x over previous
//
#include <hip/hip_runtime.h>
#include <stdint.h>

#define SEQ 8192
#define EMB 1024
#define HID 2048
#define NCH 256

#define SCAN_B 64                   // persistent blocks (1 per CU, co-resident)
#define SCAN_T 512                  // 8 waves/block
#define ROWS_PB (HID / SCAN_B)      // 32 rows of h per block
#define SUBS 16                     // threads per row
#define WPT (HID / SUBS)            // 128 weights per thread
#define SENT 0xFFFFFFFFu            // NaN bit pattern: tanh never produces it
#define FLAG_OK 1u

// ---------------------------------------------------------------------------
// Generic fp32 "TN" GEMM: C[m][n] = bias[n] + dot(X[m][:], W[n][:])
// ---------------------------------------------------------------------------
__global__ __launch_bounds__(256) void gemm_tn(const float* __restrict__ X,
                                               const float* __restrict__ W,
                                               const float* __restrict__ bias,
                                               float* __restrict__ C,
                                               int M, int N, int K)
{
    __shared__ float Xs[16][68];
    __shared__ float Ws[16][68];
    const int m0 = blockIdx.x * 64, n0 = blockIdx.y * 64;
    const int tid  = threadIdx.x;
    const int lrow = tid >> 2;
    const int kq   = (tid & 3) * 4;
    const int tx   = tid & 15, ty = tid >> 4;
    float acc[4][4] = {};
    const float* Xp = X + (size_t)(m0 + lrow) * K + kq;
    const float* Wp = W + (size_t)(n0 + lrow) * K + kq;

    for (int k0 = 0; k0 < K; k0 += 16) {
        float4 xv = *(const float4*)(Xp + k0);
        float4 wv = *(const float4*)(Wp + k0);
        __syncthreads();
        Xs[kq+0][lrow] = xv.x; Xs[kq+1][lrow] = xv.y;
        Xs[kq+2][lrow] = xv.z; Xs[kq+3][lrow] = xv.w;
        Ws[kq+0][lrow] = wv.x; Ws[kq+1][lrow] = wv.y;
        Ws[kq+2][lrow] = wv.z; Ws[kq+3][lrow] = wv.w;
        __syncthreads();
#pragma unroll
        for (int kk = 0; kk < 16; ++kk) {
            float4 av = *(const float4*)&Xs[kk][ty * 4];
            float4 bv = *(const float4*)&Ws[kk][tx * 4];
            float a[4] = {av.x, av.y, av.z, av.w};
            float b[4] = {bv.x, bv.y, bv.z, bv.w};
#pragma unroll
            for (int i = 0; i < 4; ++i)
#pragma unroll
                for (int j = 0; j < 4; ++j)
                    acc[i][j] += a[i] * b[j];
        }
    }
#pragma unroll
    for (int i = 0; i < 4; ++i) {
        const int m = m0 + ty * 4 + i;
#pragma unroll
        for (int j = 0; j < 4; ++j) {
            const int n = n0 + tx * 4 + j;
            C[(size_t)m * N + n] = acc[i][j] + bias[n];
        }
    }
}

// ---------------------------------------------------------------------------
// Persistent RNN scan, flag + write-once-data protocol:
//   Producers: 32 row-owners store h words as relaxed AGENT atomics (write-
//   through to the coherence point). __syncthreads() drains vmcnt for ALL
//   threads' stores (compiler emits s_waitcnt vmcnt(0) before s_barrier),
//   then tid0 sets flags[t][b]. Consumers: 64 lanes of wave 0 poll the 64
//   flags (64 dwords/iter/block -- 32x less traffic than data-polling), then
//   everyone reads H[t] with NORMAL float4 loads (line-granular, cacheable --
//   safe: H rows are write-once and only touched after flags say final).
//   Sentinel check + atomic-reload fallback backstops stale/prefetched lines.
// Thread (rl = tid>>4, sub = tid&15) owns row grow = b*32+rl, cols
//   col(j,e) = 64*j + 4*sub + e, j=0..31 -> 128 fp32 weights in registers.
// ---------------------------------------------------------------------------
__global__ __launch_bounds__(SCAN_T, 2) void rnn_scan(
    const int*  __restrict__ seq,
    const float* __restrict__ waa,
    const float* __restrict__ P,
    float* __restrict__ H,                 // (SEQ+1) x HID; row0 = 0, rest = SENT
    unsigned int* __restrict__ flags)      // SEQ x SCAN_B, zeroed
{
    const int b    = blockIdx.x;
    const int tid  = threadIdx.x;
    const int rl   = tid >> 4;        // 0..31
    const int sub  = tid & 15;        // 0..15
    const int grow = b * ROWS_PB + rl;

    __shared__ float hbuf[2][HID];    // 16 KB parity double-buffer

    // One-time weight load: 128 fp32 per thread, pinned into registers.
    float w[WPT];
    {
        const float* wr = waa + (size_t)grow * HID + 4 * sub;
#pragma unroll
        for (int j = 0; j < 32; ++j) {
            float4 v = *(const float4*)(wr + 64 * j);
            w[4*j+0] = v.x; w[4*j+1] = v.y; w[4*j+2] = v.z; w[4*j+3] = v.w;
        }
    }
#pragma unroll
    for (int k = 0; k < WPT; ++k) asm volatile("" : "+v"(w[k]));  // defeat remat

    unsigned* Hw = (unsigned*)H;

    for (int t = 0; t < SEQ; ++t) {
        // xa for this step (read-only, L2-cached).
        const int ch = seq[t];
        float xav = 0.f;
        if (sub == 0) xav = P[(size_t)ch * HID + grow];

        // --- wait for step t-1 completion: wave 0 polls the 64 flags ---
        if (t > 0) {
            if (tid < 64) {
                const unsigned* fl = flags + (size_t)(t - 1) * SCAN_B + tid;
                for (;;) {
                    unsigned f = __hip_atomic_load(fl, __ATOMIC_RELAXED,
                                                   __HIP_MEMORY_SCOPE_AGENT);
                    if (__ballot(f == FLAG_OK) == ~0ull) break;
                }
            }
            __syncthreads();   // gate all waves behind the detect
        }

        // --- fetch h_t: normal cacheable float4 load, sentinel backstop ---
        {
            const unsigned* p = Hw + (size_t)t * HID + tid * 4;
            uint4 v = *(const uint4*)p;
            if (v.x == SENT || v.y == SENT || v.z == SENT || v.w == SENT) {
                // rare: line was stale/prefetched -- re-read through L2 bypass
                #pragma unroll 1
                for (int e = 0; e < 4; ++e) {
                    unsigned* pe = (unsigned*)p + e;
                    unsigned ve = ((const unsigned*)&v)[e];
                    while (ve == SENT)
                        ve = __hip_atomic_load(pe, __ATOMIC_RELAXED,
                                               __HIP_MEMORY_SCOPE_AGENT);
                    ((unsigned*)&v)[e] = ve;
                }
            }
            *(uint4*)&hbuf[t & 1][tid * 4] = v;
        }
        __syncthreads();

        // --- 128 FMAs from LDS (2-way conflict float4 reads = free) ---
        float acc = 0.f;
        const float* hb = &hbuf[t & 1][4 * sub];
#pragma unroll
        for (int j = 0; j < 32; ++j) {
            float4 hv = *(const float4*)(hb + 64 * j);
            acc += w[4*j+0]*hv.x + w[4*j+1]*hv.y + w[4*j+2]*hv.z + w[4*j+3]*hv.w;
        }
        // reduce across the 16 lanes of this row
#pragma unroll
        for (int off = 8; off > 0; off >>= 1)
            acc += __shfl_xor(acc, off, 16);

        if (sub == 0) {
            float hn = tanhf(xav + acc);
            __hip_atomic_store(Hw + (size_t)(t + 1) * HID + grow,
                               __float_as_uint(hn),
                               __ATOMIC_RELAXED, __HIP_MEMORY_SCOPE_AGENT);
        }
        // Drain ALL threads' stores to the coherence point (compiler emits
        // s_waitcnt vmcnt(0) before s_barrier), then publish the flag.
        __syncthreads();
        if (tid == 0)
            __hip_atomic_store(flags + (size_t)t * SCAN_B + b, FLAG_OK,
                               __ATOMIC_RELAXED, __HIP_MEMORY_SCOPE_AGENT);
    }
}

__global__ void copy_h(const float* __restrict__ src, float* __restrict__ dst)
{
    int i = blockIdx.x * blockDim.x + threadIdx.x;
    if (i < HID) dst[i] = src[i];
}

// ---------------------------------------------------------------------------
extern "C" void kernel_launch(void* const* d_in, const int* in_sizes, int n_in,
                              void* d_out, int out_size, void* d_ws, size_t ws_size,
                              hipStream_t stream)
{
    const int*   seq  = (const int*)  d_in[0];
    const float* emb  = (const float*)d_in[1];
    const float* wax  = (const float*)d_in[2];
    const float* waxb = (const float*)d_in[3];
    const float* waa  = (const float*)d_in[4];
    const float* wya  = (const float*)d_in[5];
    const float* wyab = (const float*)d_in[6];
    float* out = (float*)d_out;

    // ws layout: H[(SEQ+1)][HID] | flags[SEQ][SCAN_B] | P[NCH][HID]
    float*        H     = (float*)d_ws;
    unsigned int* flags = (unsigned int*)((char*)d_ws + (size_t)(SEQ + 1) * HID * sizeof(float));
    float*        P     = (float*)((char*)flags + (size_t)SEQ * SCAN_B * sizeof(unsigned int));

    // Re-init every call (ws re-poisoned to 0xAA before each timed launch).
    hipMemsetAsync(H, 0, HID * sizeof(float), stream);                         // h0 = 0
    hipMemsetAsync(H + HID, 0xFF, (size_t)SEQ * HID * sizeof(float), stream);  // sentinels
    hipMemsetAsync(flags, 0, (size_t)SEQ * SCAN_B * sizeof(unsigned int), stream);

    // P = emb @ wax^T + wax_b   (M=256, N=2048, K=1024)
    dim3 gA(NCH / 64, HID / 64);
    gemm_tn<<<gA, 256, 0, stream>>>(emb, wax, waxb, P, NCH, HID, EMB);

    // Sequential recurrence (persistent, flag + write-once-data sync).
    rnn_scan<<<SCAN_B, SCAN_T, 0, stream>>>(seq, waa, P, H, flags);

    // out = H[1..SEQ] @ wya^T + wya_b   (M=8192, N=256, K=2048)
    dim3 gC(SEQ / 64, NCH / 64);
    gemm_tn<<<gC, 256, 0, stream>>>(H + HID, wya, wyab, out, SEQ, NCH, HID);

    // h_final = H[SEQ] -> tail of d_out
    copy_h<<<(HID + 255) / 256, 256, 0, stream>>>(H + (size_t)SEQ * HID,
                                                  out + (size_t)SEQ * NCH);
}

// Round 4
// 23115.291 us; speedup vs baseline: 3.9726x; 1.0199x over previous
//
#include <hip/hip_runtime.h>
#include <stdint.h>

#define SEQ 8192
#define EMB 1024
#define HID 2048
#define NCH 256

#define SCAN_B 64                   // persistent blocks (<=256 CUs, co-resident)
#define SCAN_T 512                  // 8 waves/block
#define ROWS_PB (HID / SCAN_B)      // 32 rows of h per block
#define SUBS 16                     // threads per row
#define WPT (HID / SUBS)            // 128 weights per thread
#define SENT 0xFFFFFFFFu            // poison bit pattern: tanh never produces it

// ---------------------------------------------------------------------------
// Generic fp32 "TN" GEMM: C[m][n] = bias[n] + dot(X[m][:], W[n][:])
// ---------------------------------------------------------------------------
__global__ __launch_bounds__(256) void gemm_tn(const float* __restrict__ X,
                                               const float* __restrict__ W,
                                               const float* __restrict__ bias,
                                               float* __restrict__ C,
                                               int M, int N, int K)
{
    __shared__ float Xs[16][68];
    __shared__ float Ws[16][68];
    const int m0 = blockIdx.x * 64, n0 = blockIdx.y * 64;
    const int tid  = threadIdx.x;
    const int lrow = tid >> 2;
    const int kq   = (tid & 3) * 4;
    const int tx   = tid & 15, ty = tid >> 4;
    float acc[4][4] = {};
    const float* Xp = X + (size_t)(m0 + lrow) * K + kq;
    const float* Wp = W + (size_t)(n0 + lrow) * K + kq;

    for (int k0 = 0; k0 < K; k0 += 16) {
        float4 xv = *(const float4*)(Xp + k0);
        float4 wv = *(const float4*)(Wp + k0);
        __syncthreads();
        Xs[kq+0][lrow] = xv.x; Xs[kq+1][lrow] = xv.y;
        Xs[kq+2][lrow] = xv.z; Xs[kq+3][lrow] = xv.w;
        Ws[kq+0][lrow] = wv.x; Ws[kq+1][lrow] = wv.y;
        Ws[kq+2][lrow] = wv.z; Ws[kq+3][lrow] = wv.w;
        __syncthreads();
#pragma unroll
        for (int kk = 0; kk < 16; ++kk) {
            float4 av = *(const float4*)&Xs[kk][ty * 4];
            float4 bv = *(const float4*)&Ws[kk][tx * 4];
            float a[4] = {av.x, av.y, av.z, av.w};
            float b[4] = {bv.x, bv.y, bv.z, bv.w};
#pragma unroll
            for (int i = 0; i < 4; ++i)
#pragma unroll
                for (int j = 0; j < 4; ++j)
                    acc[i][j] += a[i] * b[j];
        }
    }
#pragma unroll
    for (int i = 0; i < 4; ++i) {
        const int m = m0 + ty * 4 + i;
#pragma unroll
        for (int j = 0; j < 4; ++j) {
            const int n = n0 + tx * 4 + j;
            C[(size_t)m * N + n] = acc[i][j] + bias[n];
        }
    }
}

// ---------------------------------------------------------------------------
// Persistent RNN scan, ONE-HOP self-validating protocol:
//   H rows 1..SEQ pre-poisoned 0xFFFFFFFF. Producer lane computes its row's
//   h, fires ONE relaxed AGENT-scope dword store, and moves on -- no drain,
//   no flag, no trailing barrier. Consumers poll their 4 words of H[t] as
//   2x8B relaxed AGENT atomic loads (each dword validated independently;
//   8B tearing is harmless) with s_sleep backoff, stage into parity-buffered
//   LDS, one __syncthreads, then 128 FMAs + 16-lane reduce + tanh.
//   Parity reuse is safe: no thread reaches step t+2's LDS writes before all
//   threads pass step t+1's barrier.
// Thread (rl = tid>>4, sub = tid&15) owns row grow = b*32+rl, cols
//   col(j,e) = 64*j + 4*sub + e, j=0..31 -> 128 fp32 weights in regs/AGPRs.
// ---------------------------------------------------------------------------
__global__ __launch_bounds__(SCAN_T, 2) void rnn_scan(
    const int*  __restrict__ seq,
    const float* __restrict__ waa,
    const float* __restrict__ P,
    float* __restrict__ H)                 // (SEQ+1) x HID; row0 = 0, rest = SENT
{
    const int b    = blockIdx.x;
    const int tid  = threadIdx.x;
    const int rl   = tid >> 4;        // 0..31
    const int sub  = tid & 15;        // 0..15
    const int grow = b * ROWS_PB + rl;

    __shared__ float hbuf[2][HID];    // 16 KB parity double-buffer

    // One-time weight load: 128 fp32 per thread, pinned (AGPRs are fine).
    float w[WPT];
    {
        const float* wr = waa + (size_t)grow * HID + 4 * sub;
#pragma unroll
        for (int j = 0; j < 32; ++j) {
            float4 v = *(const float4*)(wr + 64 * j);
            w[4*j+0] = v.x; w[4*j+1] = v.y; w[4*j+2] = v.z; w[4*j+3] = v.w;
        }
    }
#pragma unroll
    for (int k = 0; k < WPT; ++k) asm volatile("" : "+v"(w[k]));  // defeat remat

    unsigned* Hw = (unsigned*)H;

    for (int t = 0; t < SEQ; ++t) {
        // xa for this step (read-only, cached) -- overlapped with the poll.
        const int ch = seq[t];
        float xav = 0.f;
        if (sub == 0) xav = P[(size_t)ch * HID + grow];

        // --- one-hop fetch of my 4 words of h_t: poll until != poison ---
        {
            const unsigned long long* p8 =
                (const unsigned long long*)(Hw + (size_t)t * HID + tid * 4);
            unsigned long long a = __hip_atomic_load(p8 + 0, __ATOMIC_RELAXED,
                                                     __HIP_MEMORY_SCOPE_AGENT);
            unsigned long long c = __hip_atomic_load(p8 + 1, __ATOMIC_RELAXED,
                                                     __HIP_MEMORY_SCOPE_AGENT);
            while (((unsigned)a == SENT) || ((unsigned)(a >> 32) == SENT) ||
                   ((unsigned)c == SENT) || ((unsigned)(c >> 32) == SENT)) {
                __builtin_amdgcn_s_sleep(1);   // ~64 cyc backoff: cut L3 poll pressure
                a = __hip_atomic_load(p8 + 0, __ATOMIC_RELAXED,
                                      __HIP_MEMORY_SCOPE_AGENT);
                c = __hip_atomic_load(p8 + 1, __ATOMIC_RELAXED,
                                      __HIP_MEMORY_SCOPE_AGENT);
            }
            uint4 v;
            v.x = (unsigned)a; v.y = (unsigned)(a >> 32);
            v.z = (unsigned)c; v.w = (unsigned)(c >> 32);
            *(uint4*)&hbuf[t & 1][tid * 4] = v;
        }
        __syncthreads();

        // --- 128 FMAs from LDS ---
        float acc = 0.f;
        const float* hb = &hbuf[t & 1][4 * sub];
#pragma unroll
        for (int j = 0; j < 32; ++j) {
            float4 hv = *(const float4*)(hb + 64 * j);
            acc += w[4*j+0]*hv.x + w[4*j+1]*hv.y + w[4*j+2]*hv.z + w[4*j+3]*hv.w;
        }
#pragma unroll
        for (int off = 8; off > 0; off >>= 1)
            acc += __shfl_xor(acc, off, 16);

        if (sub == 0) {
            float hn = tanhf(xav + acc);
            __hip_atomic_store(Hw + (size_t)(t + 1) * HID + grow,
                               __float_as_uint(hn),
                               __ATOMIC_RELAXED, __HIP_MEMORY_SCOPE_AGENT);
        }
        // no drain / no flag / no trailing barrier -- store IS the signal
    }
}

__global__ void copy_h(const float* __restrict__ src, float* __restrict__ dst)
{
    int i = blockIdx.x * blockDim.x + threadIdx.x;
    if (i < HID) dst[i] = src[i];
}

// ---------------------------------------------------------------------------
extern "C" void kernel_launch(void* const* d_in, const int* in_sizes, int n_in,
                              void* d_out, int out_size, void* d_ws, size_t ws_size,
                              hipStream_t stream)
{
    const int*   seq  = (const int*)  d_in[0];
    const float* emb  = (const float*)d_in[1];
    const float* wax  = (const float*)d_in[2];
    const float* waxb = (const float*)d_in[3];
    const float* waa  = (const float*)d_in[4];
    const float* wya  = (const float*)d_in[5];
    const float* wyab = (const float*)d_in[6];
    float* out = (float*)d_out;

    // ws layout: H[(SEQ+1)][HID] fp32 | P[NCH][HID] fp32
    float* H = (float*)d_ws;
    float* P = (float*)((char*)d_ws + (size_t)(SEQ + 1) * HID * sizeof(float));

    // Re-init every call: row 0 = h0 = 0; rows 1..SEQ = poison.
    hipMemsetAsync(H, 0, HID * sizeof(float), stream);
    hipMemsetAsync(H + HID, 0xFF, (size_t)SEQ * HID * sizeof(float), stream);

    // P = emb @ wax^T + wax_b   (M=256, N=2048, K=1024)
    dim3 gA(NCH / 64, HID / 64);
    gemm_tn<<<gA, 256, 0, stream>>>(emb, wax, waxb, P, NCH, HID, EMB);

    // Sequential recurrence (persistent, one-hop self-validating sync).
    rnn_scan<<<SCAN_B, SCAN_T, 0, stream>>>(seq, waa, P, H);

    // out = H[1..SEQ] @ wya^T + wya_b   (M=8192, N=256, K=2048)
    dim3 gC(SEQ / 64, NCH / 64);
    gemm_tn<<<gC, 256, 0, stream>>>(H + HID, wya, wyab, out, SEQ, NCH, HID);

    // h_final = H[SEQ] -> tail of d_out
    copy_h<<<(HID + 255) / 256, 256, 0, stream>>>(H + (size_t)SEQ * HID,
                                                  out + (size_t)SEQ * NCH);
}